// Round 16
// baseline (1381.151 us; speedup 1.0000x reference)
//
#include <hip/hip_runtime.h>
#include <hip/hip_bf16.h>

typedef unsigned short u16;
typedef unsigned int u32;
typedef unsigned long long u64;
typedef __bf16 bf16x8 __attribute__((ext_vector_type(8)));
typedef float f32x4 __attribute__((ext_vector_type(4)));

#define NB 64
#define NT 128
#define NF 1024
#define NH 1024
#define NK 2048
#define NG 4096
#define NBH (NB * NH)

#define FSTR 16   // flags: one u32 per 64B line

// LDS: W 128 KiB + zsx[4][2][16][20] f32 + zhs[4][16][20] f32 + stamps
#define W_LDS_BYTES 131072
#define ZSX_BYTES (4 * 2 * 16 * 20 * 4)   // 10240
#define ZHS_BYTES (4 * 16 * 20 * 4)       // 5120
#define ST_BYTES 64
#define SMEM_BYTES (W_LDS_BYTES + ZSX_BYTES + ZHS_BYTES + ST_BYTES)  // 146496

// stamps: st[0..3] = xs[w] (zsx[w][(v-1)&1] holds zx(v-1)); st[4..7] = pw[w]
__device__ __forceinline__ void st_rel(u32* p, u32 v) {
  __hip_atomic_store(p, v, __ATOMIC_RELEASE, __HIP_MEMORY_SCOPE_WORKGROUP);
}
__device__ __forceinline__ u32 ld_acq(u32* p) {
  return __hip_atomic_load(p, __ATOMIC_ACQUIRE, __HIP_MEMORY_SCOPE_WORKGROUP);
}
__device__ __forceinline__ void spin_ge(u32* p, u32 v) {
  while (ld_acq(p) < v) {}
}

__device__ __forceinline__ u16 f2bf(float f) {
  unsigned u = __builtin_bit_cast(unsigned, f);
  u = (u + 0x7FFFu + ((u >> 16) & 1u)) >> 16;
  return (u16)u;
}
__device__ __forceinline__ float bf2f(u16 v) {
  unsigned u = ((unsigned)v) << 16;
  return __builtin_bit_cast(float, u);
}

// ---------------- prep: x fp32 -> bf16 ----------------
__global__ __launch_bounds__(256) void lstm_cvt_x(const float* __restrict__ x,
                                                  u16* __restrict__ xb) {
  int i = (blockIdx.x * 256 + threadIdx.x) * 4;
  float4 v = *reinterpret_cast<const float4*>(x + i);
  ushort4 o;
  o.x = f2bf(v.x); o.y = f2bf(v.y); o.z = f2bf(v.z); o.w = f2bf(v.w);
  *reinterpret_cast<ushort4*>(xb + i) = o;
}

// ---------------- prep: W -> per-block LDS-image slices (verified R3-R15) ----
__global__ __launch_bounds__(256) void lstm_prep_w(const float* __restrict__ W,
                                                   u16* __restrict__ wt_blk) {
  __shared__ float tile[32][33];
  int n0 = blockIdx.x * 32;
  int k0 = blockIdx.y * 32;
  int tc = threadIdx.x & 31;
  int tr = threadIdx.x >> 5;
#pragma unroll
  for (int i = 0; i < 4; ++i) {
    int k = tr + i * 8;
    tile[k][tc] = W[(size_t)(k0 + k) * NG + n0 + tc];
  }
  __syncthreads();
#pragma unroll
  for (int i = 0; i < 4; ++i) {
    int n = n0 + tr + i * 8;
    float wv = tile[tc][tr + i * 8];
    int k = k0 + tc;
    int g = n >> 10, col = n & 1023;
    int b = col >> 2, brow = g * 4 + (col & 3);
    int kh = k >> 10, ch = (k & 1023) >> 5;
    int slot = (k >> 3) & 3, elem = k & 7;
    size_t base = (size_t)b * 65536 + (size_t)(kh * 32 + ch) * 512
                + (size_t)(slot * 16 + brow) * 8 + elem;
    u16 hi = f2bf(wv);
    wt_blk[base] = hi;
    wt_blk[base + 32768] = f2bf(wv - bf2f(hi));
  }
}

// ---------------- persistent LSTM: M-split, barrier-free step loop -------------
// 256 blocks x 512 threads. Pairs: x-wave w (0-3) <-> h-wave w (waves 4-7),
// both own output rows [16w, 16w+16) x the block's 16 gate-cols, FULL K.
// x-wave w: zx(t+1) -> private zsx[w][(t+1)&1] (LDS), stamp xs[w]; runs 1 ahead.
// h-wave w: poll 256 flags [t][p][w] -> load h rows (slab layout) -> 64 MFMA
// (4 chains) -> wave-private LDS transpose -> pointwise (1 out/lane) ->
// 128B-coalesced u16 publish -> vmcnt(0) -> own flag. NO __syncthreads in loop.
__global__ __launch_bounds__(512) void lstm_persist(
    const u16* __restrict__ xb, u16* __restrict__ hseq,
    const u16* __restrict__ wt_blk, const float* __restrict__ bias,
    float* __restrict__ out, u32* __restrict__ flags,
    float* __restrict__ zo) {
  extern __shared__ char smem[];
  u16* Wl = (u16*)smem;
  float* zsxL = (float*)(smem + W_LDS_BYTES);
  float* zhsL = (float*)(smem + W_LDS_BYTES + ZSX_BYTES);
  u32* st = (u32*)(smem + W_LDS_BYTES + ZSX_BYTES + ZHS_BYTES);

  const int b = blockIdx.x;
  const int tid = threadIdx.x;
  const int lane = tid & 63;
  const int wv_ = tid >> 6;
  const bool is_x = (wv_ < 4);
  const int w = wv_ & 3;

  // ---- load W slice (128 KiB) into LDS ----
  {
    const u16* src = wt_blk + (size_t)b * 65536;
#pragma unroll
    for (int it = 0; it < 16; ++it) {
      uint4 v = *reinterpret_cast<const uint4*>(src + (size_t)it * 4096 + tid * 8);
      *reinterpret_cast<uint4*>(Wl + (size_t)it * 4096 + tid * 8) = v;
    }
  }
  if (tid < 16) st[tid] = 0u;

  const int c16 = lane & 15;          // MFMA col (gate-col)
  const int mg4 = (lane >> 4) * 4;    // C-layout row group
  const int g2 = 2 * (lane >> 4);

  // x-wave bias fold (per gate-col): bv = bias[gate*1024 + b*4 + hc] (+1 forget)
  float bv = 0.f;
  if (is_x) {
    const int g = c16 >> 2, hc = b * 4 + (c16 & 3);
    bv = bias[g * NH + hc] + (g == 2 ? 1.0f : 0.0f);
  }
  // h-wave pointwise ownership: 1 output per lane
  const int orow = lane >> 2;         // 0..15
  const int ocol = lane & 3;          // 0..3
  float creg = 0.f;
  __syncthreads();  // W + stamps ready (prologue only)

  if (is_x) {
    // =================== x-wave w ===================
    const int row = 16 * w + c16;
    const u16* abase = xb + (size_t)row * NT * NF + 8 * (lane >> 4);
    float* zdst0 = zsxL + ((size_t)(w * 2 + 0) * 16 + c16) * 20 + mg4;
    float* zdst1 = zsxL + ((size_t)(w * 2 + 1) * 16 + c16) * 20 + mg4;

#pragma unroll 1
    for (int t = 0; t <= NT - 1; ++t) {
      // iteration t computes zx(t) into buf t&1 (prologue-style: first iter free)
      if (t >= 2) spin_ge(&st[4 + w], (u32)(t - 1));  // pointwise(t-2) done
      const u16* a0 = abase + (size_t)t * NF;
      f32x4 c0 = {}, c1 = {}, c2 = {}, c3 = {};
#pragma unroll
      for (int half = 0; half < 2; ++half) {
        bf16x8 F[16];
#pragma unroll
        for (int cc = 0; cc < 16; ++cc)
          F[cc] = *reinterpret_cast<const bf16x8*>(a0 + (half * 16 + cc) * 32);
#pragma unroll
        for (int cc = 0; cc < 16; ++cc) {
          const int ch = half * 16 + cc;
          const bf16x8 wh = *reinterpret_cast<const bf16x8*>(
              Wl + (size_t)ch * 512 + lane * 8);
          const bf16x8 wl2 = *reinterpret_cast<const bf16x8*>(
              Wl + (size_t)(64 + ch) * 512 + lane * 8);
          if (cc & 1) {
            c1 = __builtin_amdgcn_mfma_f32_16x16x32_bf16(F[cc], wh, c1, 0, 0, 0);
            c3 = __builtin_amdgcn_mfma_f32_16x16x32_bf16(F[cc], wl2, c3, 0, 0, 0);
          } else {
            c0 = __builtin_amdgcn_mfma_f32_16x16x32_bf16(F[cc], wh, c0, 0, 0, 0);
            c2 = __builtin_amdgcn_mfma_f32_16x16x32_bf16(F[cc], wl2, c2, 0, 0, 0);
          }
        }
      }
      f32x4 acc;
#pragma unroll
      for (int r = 0; r < 4; ++r)
        acc[r] = (c0[r] + c1[r]) + (c2[r] + c3[r]) + bv;
      *reinterpret_cast<f32x4*>((t & 1) ? zdst1 : zdst0) = acc;
      st_rel(&st[w], (u32)(t + 1));   // zx(t) ready
    }
  } else {
    // =================== h-wave w ===================
    const int row = 16 * w + c16;
    float* zhw = zhsL + ((size_t)w * 16 + c16) * 20 + mg4;

#pragma unroll 1
    for (int t = 0; t < NT; ++t) {
      f32x4 acc = {};
      if (t > 0) {
        // ---- poll 256 producer flags for slice w (4 per lane, paced) ----
        const u32* fp = flags + ((size_t)t * 1024 + lane * 16 + w) * FSTR;
        u32 a0f, a1f, a2f, a3f;
        a0f = __hip_atomic_load(fp,              __ATOMIC_RELAXED, __HIP_MEMORY_SCOPE_AGENT);
        a1f = __hip_atomic_load(fp + 4 * FSTR,   __ATOMIC_RELAXED, __HIP_MEMORY_SCOPE_AGENT);
        a2f = __hip_atomic_load(fp + 8 * FSTR,   __ATOMIC_RELAXED, __HIP_MEMORY_SCOPE_AGENT);
        a3f = __hip_atomic_load(fp + 12 * FSTR,  __ATOMIC_RELAXED, __HIP_MEMORY_SCOPE_AGENT);
        while (!__all((a0f & a1f & a2f & a3f) != 0)) {
          __builtin_amdgcn_s_sleep(1);
          a0f = __hip_atomic_load(fp,             __ATOMIC_RELAXED, __HIP_MEMORY_SCOPE_AGENT);
          a1f = __hip_atomic_load(fp + 4 * FSTR,  __ATOMIC_RELAXED, __HIP_MEMORY_SCOPE_AGENT);
          a2f = __hip_atomic_load(fp + 8 * FSTR,  __ATOMIC_RELAXED, __HIP_MEMORY_SCOPE_AGENT);
          a3f = __hip_atomic_load(fp + 12 * FSTR, __ATOMIC_RELAXED, __HIP_MEMORY_SCOPE_AGENT);
        }

        // ---- h-GEMM: rows [16w,16w+16), full K=1024, 4 acc chains ----
        const u64* hb = reinterpret_cast<const u64*>(hseq) + (size_t)t * 16384;
        f32x4 c0 = {}, c1 = {}, c2 = {}, c3 = {};
        __builtin_amdgcn_s_setprio(1);
#pragma unroll
        for (int half = 0; half < 2; ++half) {
          u64 L[16], H[16];
#pragma unroll
          for (int cc = 0; cc < 16; ++cc) {
            const int s = (half * 16 + cc) * 8 + g2;
            L[cc] = hb[(size_t)s * 64 + row];
            H[cc] = hb[(size_t)(s + 1) * 64 + row];
          }
#pragma unroll
          for (int cc = 0; cc < 16; ++cc) {
            const int ch = half * 16 + cc;
            const bf16x8 wh = *reinterpret_cast<const bf16x8*>(
                Wl + (size_t)(32 + ch) * 512 + lane * 8);
            const bf16x8 wl2 = *reinterpret_cast<const bf16x8*>(
                Wl + (size_t)(96 + ch) * 512 + lane * 8);
            union HU { u64 q[2]; bf16x8 f; } u;
            u.q[0] = L[cc];
            u.q[1] = H[cc];
            if (cc & 1) {
              c1 = __builtin_amdgcn_mfma_f32_16x16x32_bf16(u.f, wh, c1, 0, 0, 0);
              c3 = __builtin_amdgcn_mfma_f32_16x16x32_bf16(u.f, wl2, c3, 0, 0, 0);
            } else {
              c0 = __builtin_amdgcn_mfma_f32_16x16x32_bf16(u.f, wh, c0, 0, 0, 0);
              c2 = __builtin_amdgcn_mfma_f32_16x16x32_bf16(u.f, wl2, c2, 0, 0, 0);
            }
          }
        }
        __builtin_amdgcn_s_setprio(0);
#pragma unroll
        for (int r = 0; r < 4; ++r) acc[r] = (c0[r] + c1[r]) + (c2[r] + c3[r]);
      }

      // ---- wave-private transpose via LDS (no barrier, lgkmcnt only) ----
      *reinterpret_cast<f32x4*>(zhw) = acc;
      asm volatile("s_waitcnt lgkmcnt(0)" ::: "memory");
      float zh[4];
#pragma unroll
      for (int g = 0; g < 4; ++g)
        zh[g] = zhsL[((size_t)w * 16 + g * 4 + ocol) * 20 + orow];

      // ---- zsx (bias folded) from x-wave partner ----
      spin_ge(&st[w], (u32)(t + 1));
      float zx[4];
      const size_t zb = (size_t)(w * 2 + (t & 1)) * 16;
#pragma unroll
      for (int g = 0; g < 4; ++g)
        zx[g] = zsxL[(zb + g * 4 + ocol) * 20 + orow];
      st_rel(&st[4 + w], (u32)(t + 1));  // buffer consumed

      // ---- pointwise: one (row, col) per lane ----
      const float zi = zh[0] + zx[0];
      const float zj = zh[1] + zx[1];
      const float zf = zh[2] + zx[2];
      const float zo4 = zh[3] + zx[3];
      const float si = 1.f / (1.f + __expf(-zi));
      const float tj = tanhf(zj);
      const float sf = 1.f / (1.f + __expf(-zf));   // forget bias folded in zx
      const float so = 1.f / (1.f + __expf(-zo4));
      const float cn = creg * sf + si * tj;
      const float hn = tanhf(cn) * so;
      creg = cn;

      // ---- publish: 64 lanes x u16 = 128 B contiguous; own flag ----
      if (t < NT - 1) {
        __hip_atomic_store(
            hseq + ((size_t)(t + 1) * 256 + b) * 256 + (16 * w + orow) * 4 + ocol,
            f2bf(hn), __ATOMIC_RELAXED, __HIP_MEMORY_SCOPE_AGENT);
        asm volatile("s_waitcnt vmcnt(0)" ::: "memory");
        if (lane == 0)
          __hip_atomic_store(&flags[((size_t)(t + 1) * 1024 + b * 4 + w) * FSTR],
                             1u, __ATOMIC_RELAXED, __HIP_MEMORY_SCOPE_AGENT);
      }
      // staged output (off critical path)
      __hip_atomic_store(
          reinterpret_cast<u32*>(zo + ((size_t)t * NH + b * 4 + ocol) * NB
                                 + 16 * w + orow),
          __builtin_bit_cast(u32, hn), __ATOMIC_RELAXED, __HIP_MEMORY_SCOPE_AGENT);
    }
  }

  // ================= final: grid rendezvous, then zo -> out transpose =========
  __syncthreads();
  asm volatile("s_waitcnt vmcnt(0)" ::: "memory");  // all zo stores at LLC
  if (tid == 0)
    __hip_atomic_store(&flags[(size_t)b * 4 * FSTR], 1u, __ATOMIC_RELAXED,
                       __HIP_MEMORY_SCOPE_AGENT);  // done flag (t=0 region)
  if (wv_ == 0) {
    bool ok;
    do {
      u32 v0 = __hip_atomic_load(flags + (size_t)(lane * 4 + 0) * 4 * FSTR, __ATOMIC_RELAXED, __HIP_MEMORY_SCOPE_AGENT);
      u32 v1 = __hip_atomic_load(flags + (size_t)(lane * 4 + 1) * 4 * FSTR, __ATOMIC_RELAXED, __HIP_MEMORY_SCOPE_AGENT);
      u32 v2 = __hip_atomic_load(flags + (size_t)(lane * 4 + 2) * 4 * FSTR, __ATOMIC_RELAXED, __HIP_MEMORY_SCOPE_AGENT);
      u32 v3 = __hip_atomic_load(flags + (size_t)(lane * 4 + 3) * 4 * FSTR, __ATOMIC_RELAXED, __HIP_MEMORY_SCOPE_AGENT);
      ok = ((v0 & v1 & v2 & v3) == 1u);
      if (!__all(ok)) __builtin_amdgcn_s_sleep(1);
    } while (!__all(ok));
  }
  __syncthreads();

  // block b: slab ts = b>>1, rows [r0, r0+32). LDS tile reuses smem.
  {
    const int ts = b >> 1;
    const int r0 = (b & 1) * 32;
    float* T = (float*)smem;  // [32][1028] floats = 131584 B < SMEM_BYTES
#pragma unroll 4
    for (int it = 0; it < 16; ++it) {
      int flat = it * 512 + tid;
      int c = flat >> 3;
      int q = flat & 7;
      const u64* p = reinterpret_cast<const u64*>(
          zo + ((size_t)ts * NH + c) * NB + r0 + q * 4);
      u64 lo = __hip_atomic_load(p + 0, __ATOMIC_RELAXED, __HIP_MEMORY_SCOPE_AGENT);
      u64 hi = __hip_atomic_load(p + 1, __ATOMIC_RELAXED, __HIP_MEMORY_SCOPE_AGENT);
      T[(q * 4 + 0) * 1028 + c] = __builtin_bit_cast(float, (u32)lo);
      T[(q * 4 + 1) * 1028 + c] = __builtin_bit_cast(float, (u32)(lo >> 32));
      T[(q * 4 + 2) * 1028 + c] = __builtin_bit_cast(float, (u32)hi);
      T[(q * 4 + 3) * 1028 + c] = __builtin_bit_cast(float, (u32)(hi >> 32));
    }
    __syncthreads();
#pragma unroll 4
    for (int it = 0; it < 16; ++it) {
      int flat = it * 512 + tid;
      int r = flat >> 8;
      int c4 = flat & 255;
      float4 v;
      v.x = T[r * 1028 + c4 * 4 + 0];
      v.y = T[r * 1028 + c4 * 4 + 1];
      v.z = T[r * 1028 + c4 * 4 + 2];
      v.w = T[r * 1028 + c4 * 4 + 3];
      *reinterpret_cast<float4*>(
          out + ((size_t)(r0 + r) * NT + ts) * NH + c4 * 4) = v;
    }
  }
}

extern "C" void kernel_launch(void* const* d_in, const int* in_sizes, int n_in,
                              void* d_out, int out_size, void* d_ws, size_t ws_size,
                              hipStream_t stream) {
  const float* x = (const float*)d_in[0];
  const float* W = (const float*)d_in[1];
  const float* bias = (const float*)d_in[2];
  float* out = (float*)d_out;

  char* ws = (char*)d_ws;
  u16* xb = (u16*)(ws);                                  // 16 MiB
  u16* wt_blk = (u16*)(ws + 16777216);                   // 32 MiB
  u16* hseq = (u16*)(ws + 50331648);                     // 16 MiB (slab layout)
  u32* flags = (u32*)(ws + 67108864);                    // 32 MiB (NT*1024*FSTR*4)
  float* zo = (float*)(ws + 67108864 + 33554432);        // 32 MiB (col-major staging)

  hipMemsetAsync(flags, 0, (size_t)NT * 1024 * FSTR * 4, stream);  // per-replay

  lstm_cvt_x<<<(NB * NT * NF) / (256 * 4), 256, 0, stream>>>(x, xb);
  lstm_prep_w<<<dim3(NG / 32, NK / 32), 256, 0, stream>>>(W, wt_blk);

  hipFuncSetAttribute((const void*)lstm_persist,
                      hipFuncAttributeMaxDynamicSharedMemorySize, SMEM_BYTES);

  void* args[] = {(void*)&xb, (void*)&hseq, (void*)&wt_blk, (void*)&bias,
                  (void*)&out, (void*)&flags, (void*)&zo};
  hipLaunchCooperativeKernel((void*)lstm_persist, dim3(256), dim3(512), args,
                             SMEM_BYTES, stream);
}

// Round 17
// 1262.541 us; speedup vs baseline: 1.0939x; 1.0939x over previous
//
#include <hip/hip_runtime.h>
#include <hip/hip_bf16.h>

typedef unsigned short u16;
typedef unsigned int u32;
typedef unsigned long long u64;
typedef __bf16 bf16x8 __attribute__((ext_vector_type(8)));
typedef float f32x4 __attribute__((ext_vector_type(4)));

#define NB 64
#define NT 128
#define NF 1024
#define NH 1024
#define NK 2048
#define NG 4096
#define NBH (NB * NH)

#define FSTR 16   // flags: one u32 per 64B line

// LDS: W 128 KiB + zsx[2 buf][2][64][17] + zsh[2][64][17] + stamps
#define W_LDS_BYTES 131072
#define ZSX_BYTES (2 * 2 * 64 * 17 * 4)   // 17408
#define ZSH_BYTES (2 * 64 * 17 * 4)       // 8704
#define ST_BYTES 64
#define SMEM_BYTES (W_LDS_BYTES + ZSX_BYTES + ZSH_BYTES + ST_BYTES)  // 157248

// stamps (monotonic, single-writer, init 0):
// st[0..1]=x write regions 0,1   st[2..3]=x add complete (zx(v-1) ready)
// st[4..5]=zsh write (waves 4,5) st[6..7]=zsh add complete (waves 6,7)
// st[8..9]=pointwise done (waves 4,5): value v => step v-1 published+drained
__device__ __forceinline__ void st_rel(u32* p, u32 v) {
  __hip_atomic_store(p, v, __ATOMIC_RELEASE, __HIP_MEMORY_SCOPE_WORKGROUP);
}
__device__ __forceinline__ u32 ld_acq(u32* p) {
  return __hip_atomic_load(p, __ATOMIC_ACQUIRE, __HIP_MEMORY_SCOPE_WORKGROUP);
}
__device__ __forceinline__ void spin_ge(u32* p, u32 v) {
  while (ld_acq(p) < v) {}
}

__device__ __forceinline__ u16 f2bf(float f) {
  unsigned u = __builtin_bit_cast(unsigned, f);
  u = (u + 0x7FFFu + ((u >> 16) & 1u)) >> 16;
  return (u16)u;
}
__device__ __forceinline__ float bf2f(u16 v) {
  unsigned u = ((unsigned)v) << 16;
  return __builtin_bit_cast(float, u);
}

// ---------------- prep: x fp32 -> bf16 ----------------
__global__ __launch_bounds__(256) void lstm_cvt_x(const float* __restrict__ x,
                                                  u16* __restrict__ xb) {
  int i = (blockIdx.x * 256 + threadIdx.x) * 4;
  float4 v = *reinterpret_cast<const float4*>(x + i);
  ushort4 o;
  o.x = f2bf(v.x); o.y = f2bf(v.y); o.z = f2bf(v.z); o.w = f2bf(v.w);
  *reinterpret_cast<ushort4*>(xb + i) = o;
}

// ---------------- prep: W -> per-block LDS-image slices (verified R3-R15) ----
__global__ __launch_bounds__(256) void lstm_prep_w(const float* __restrict__ W,
                                                   u16* __restrict__ wt_blk) {
  __shared__ float tile[32][33];
  int n0 = blockIdx.x * 32;
  int k0 = blockIdx.y * 32;
  int tc = threadIdx.x & 31;
  int tr = threadIdx.x >> 5;
#pragma unroll
  for (int i = 0; i < 4; ++i) {
    int k = tr + i * 8;
    tile[k][tc] = W[(size_t)(k0 + k) * NG + n0 + tc];
  }
  __syncthreads();
#pragma unroll
  for (int i = 0; i < 4; ++i) {
    int n = n0 + tr + i * 8;
    float wv = tile[tc][tr + i * 8];
    int k = k0 + tc;
    int g = n >> 10, col = n & 1023;
    int b = col >> 2, brow = g * 4 + (col & 3);
    int kh = k >> 10, ch = (k & 1023) >> 5;
    int slot = (k >> 3) & 3, elem = k & 7;
    size_t base = (size_t)b * 65536 + (size_t)(kh * 32 + ch) * 512
                + (size_t)(slot * 16 + brow) * 8 + elem;
    u16 hi = f2bf(wv);
    wt_blk[base] = hi;
    wt_blk[base + 32768] = f2bf(wv - bf2f(hi));
  }
}

// x A-pass: 4 M-frags, K=256 slice, hi+lo MFMA, 2-stage pipeline (verified).
__device__ __forceinline__ void mfma_pass(const u16* __restrict__ a0, size_t rstride,
                                          const u16* __restrict__ Wl, int khalf,
                                          int kq, int lane, f32x4 acc[4]) {
  bf16x8 pf[4], qf[4];
#pragma unroll
  for (int i = 0; i < 4; ++i)
    pf[i] = *reinterpret_cast<const bf16x8*>(a0 + (size_t)i * 16 * rstride);
#pragma unroll
  for (int cc = 0; cc < 8; ++cc) {
    if (cc < 7) {
#pragma unroll
      for (int i = 0; i < 4; ++i)
        qf[i] = *reinterpret_cast<const bf16x8*>(a0 + (size_t)i * 16 * rstride + (cc + 1) * 32);
    }
    const int ch = kq * 8 + cc;
    const bf16x8 wh = *reinterpret_cast<const bf16x8*>(
        Wl + (size_t)(khalf * 32 + ch) * 512 + lane * 8);
    const bf16x8 wl2 = *reinterpret_cast<const bf16x8*>(
        Wl + (size_t)(64 + khalf * 32 + ch) * 512 + lane * 8);
#pragma unroll
    for (int i = 0; i < 4; ++i)
      acc[i] = __builtin_amdgcn_mfma_f32_16x16x32_bf16(pf[i], wh, acc[i], 0, 0, 0);
#pragma unroll
    for (int i = 0; i < 4; ++i)
      acc[i] = __builtin_amdgcn_mfma_f32_16x16x32_bf16(pf[i], wl2, acc[i], 0, 0, 0);
#pragma unroll
    for (int i = 0; i < 4; ++i) pf[i] = qf[i];
  }
}

// ---------------- persistent LSTM: R15 exchange + barrier-free stamp loop -------
// 256 blocks x 512 threads. x-waves 0-3: zx(t) into zsx[t&1] (write 0,1 / add
// 2,3 via stamps), gated only by pointwise(t-2). h-waves 4-7: poll 64 producer
// flags (line-padded, paced) -> slab bulk load -> MFMA; waves 4,5 write zsh,
// then do the pointwise + 256B-coalesced publish + own drain; wave 4 posts the
// block flag after wave 5's stamp. Waves 6,7 add zsh then pre-poll step t+1.
// NO __syncthreads in the step loop.
__global__ __launch_bounds__(512) void lstm_persist(
    const u16* __restrict__ xb, u16* __restrict__ hseq,
    const u16* __restrict__ wt_blk, const float* __restrict__ bias,
    float* __restrict__ out, u32* __restrict__ flags,
    float* __restrict__ zo) {
  extern __shared__ char smem[];
  u16* Wl = (u16*)smem;
  float (*zsx)[2][64][17] = (float(*)[2][64][17])(smem + W_LDS_BYTES);
  float (*zsh)[64][17] = (float(*)[64][17])(smem + W_LDS_BYTES + ZSX_BYTES);
  u32* st = (u32*)(smem + W_LDS_BYTES + ZSX_BYTES + ZSH_BYTES);

  const int b = blockIdx.x;
  const int tid = threadIdx.x;
  const int lane = tid & 63;
  const int wv_ = tid >> 6;
  const bool is_x = (wv_ < 4);
  const int kq = wv_ & 3;     // K-quarter for both roles
  const int hq = wv_ - 4;     // h-wave index 0..3 (valid when !is_x)

  // ---- load W slice (128 KiB) into LDS ----
  {
    const u16* src = wt_blk + (size_t)b * 65536;
#pragma unroll
    for (int it = 0; it < 16; ++it) {
      uint4 v = *reinterpret_cast<const uint4*>(src + (size_t)it * 4096 + tid * 8);
      *reinterpret_cast<uint4*>(Wl + (size_t)it * 4096 + tid * 8) = v;
    }
  }
  for (int i = tid; i < 2 * 64 * 17; i += 512) ((float*)zsh)[i] = 0.f;
  if (tid < 16) st[tid] = 0u;

  const int arow = lane & 15;
  const int kfr = 8 * (lane >> 4);
  const int kbase = kq * 256 + kfr;
  const int zn = lane & 15;
  const int mg = (lane >> 4) * 4;

  // pointwise ownership (waves 4,5): idx = hq*64 + lane -> (prow, 2 cols)
  const int idx = hq * 64 + lane;       // only meaningful for hq in {0,1}
  const int prow = (idx & 127) >> 1;
  const int pc = (idx & 1) * 2;
  const int gc0 = b * 4 + pc;
  float bz[2][4];
  float creg[2] = {0.f, 0.f};
  if (!is_x && hq < 2) {
#pragma unroll
    for (int j = 0; j < 2; ++j) {
      bz[j][0] = bias[gc0 + j];
      bz[j][1] = bias[NH + gc0 + j];
      bz[j][2] = bias[2 * NH + gc0 + j];
      bz[j][3] = bias[3 * NH + gc0 + j];
    }
  }
  __syncthreads();  // prologue only: W, zsh zeros, stamps visible

  if (is_x) {
    // =================== x-wave kq: zx(t) one step ahead ===================
#pragma unroll 1
    for (int t = 0; t < NT; ++t) {
      if (t >= 2) {             // WAR: pointwise(t-2) finished reading buf t&1
        spin_ge(&st[8], (u32)(t - 1));
        spin_ge(&st[9], (u32)(t - 1));
      }
      f32x4 acc[4] = {};
      const u16* a0 = xb + ((size_t)arow * NT + t) * NF + kbase;
      mfma_pass(a0, (size_t)NT * NF, Wl, 0, kq, lane, acc);
      const int buf = t & 1;
      if (kq < 2) {
#pragma unroll
        for (int i = 0; i < 4; ++i)
#pragma unroll
          for (int r = 0; r < 4; ++r) zsx[buf][kq][i * 16 + mg + r][zn] = acc[i][r];
        st_rel(&st[kq], (u32)(t + 1));
      } else {
        spin_ge(&st[kq - 2], (u32)(t + 1));
#pragma unroll
        for (int i = 0; i < 4; ++i)
#pragma unroll
          for (int r = 0; r < 4; ++r) zsx[buf][kq - 2][i * 16 + mg + r][zn] += acc[i][r];
        st_rel(&st[kq], (u32)(t + 1));   // st[2], st[3]
      }
    }
  } else {
    // =================== h-wave kq ===================
#pragma unroll 1
    for (int t = 0; t < NT; ++t) {
      f32x4 acc[4] = {};
      if (t > 0) {
        // poll 64 producer flags (line-padded, s_sleep-paced)
        const u32* fp = flags + ((size_t)t * 256 + kq * 64 + lane) * FSTR;
        u32 v = __hip_atomic_load(fp, __ATOMIC_RELAXED, __HIP_MEMORY_SCOPE_AGENT);
        while (!__all(v != 0)) {
          __builtin_amdgcn_s_sleep(1);
          v = __hip_atomic_load(fp, __ATOMIC_RELAXED, __HIP_MEMORY_SCOPE_AGENT);
        }
        // slab-layout h-GEMM (verified R14/R15)
        const u64* hb = reinterpret_cast<const u64*>(hseq) + (size_t)t * (256 * 64);
        const int sbase = kq * 64 + 2 * (lane >> 4);
        u64 plo[4], phi[4], qlo[4], qhi[4];
#pragma unroll
        for (int i = 0; i < 4; ++i) {
          plo[i] = hb[(size_t)sbase * 64 + arow + 16 * i];
          phi[i] = hb[(size_t)(sbase + 1) * 64 + arow + 16 * i];
        }
        __builtin_amdgcn_s_setprio(1);
#pragma unroll
        for (int cc = 0; cc < 8; ++cc) {
          if (cc < 7) {
            const int s = sbase + (cc + 1) * 8;
#pragma unroll
            for (int i = 0; i < 4; ++i) {
              qlo[i] = hb[(size_t)s * 64 + arow + 16 * i];
              qhi[i] = hb[(size_t)(s + 1) * 64 + arow + 16 * i];
            }
          }
          const int ch = kq * 8 + cc;
          const bf16x8 wh = *reinterpret_cast<const bf16x8*>(
              Wl + (size_t)(32 + ch) * 512 + lane * 8);
          const bf16x8 wlo = *reinterpret_cast<const bf16x8*>(
              Wl + (size_t)(96 + ch) * 512 + lane * 8);
#pragma unroll
          for (int i = 0; i < 4; ++i) {
            union HU { u64 q[2]; bf16x8 f; } u;
            u.q[0] = plo[i];
            u.q[1] = phi[i];
            acc[i] = __builtin_amdgcn_mfma_f32_16x16x32_bf16(u.f, wh, acc[i], 0, 0, 0);
            acc[i] = __builtin_amdgcn_mfma_f32_16x16x32_bf16(u.f, wlo, acc[i], 0, 0, 0);
          }
#pragma unroll
          for (int i = 0; i < 4; ++i) { plo[i] = qlo[i]; phi[i] = qhi[i]; }
        }
        __builtin_amdgcn_s_setprio(0);
      }

      if (hq < 2) {
        // ---- zsh write (WAR: other pointwise wave finished step t-1) ----
        spin_ge(&st[8 + (1 - hq)], (u32)t);
        if (t > 0) {
#pragma unroll
          for (int i = 0; i < 4; ++i)
#pragma unroll
            for (int r = 0; r < 4; ++r) zsh[hq][i * 16 + mg + r][zn] = acc[i][r];
        }
        st_rel(&st[4 + hq], (u32)(t + 1));

        // ---- pointwise: wait zsh adds + zsx(t) complete ----
        spin_ge(&st[6], (u32)(t + 1));
        spin_ge(&st[7], (u32)(t + 1));
        spin_ge(&st[2], (u32)(t + 1));
        spin_ge(&st[3], (u32)(t + 1));
        const int cb = t & 1;
        float hn[2];
#pragma unroll
        for (int jj = 0; jj < 2; ++jj) {
          const int col = pc + jj;
          const float zi = zsx[cb][0][prow][col]      + zsx[cb][1][prow][col]      + zsh[0][prow][col]      + zsh[1][prow][col]      + bz[jj][0];
          const float zj = zsx[cb][0][prow][4 + col]  + zsx[cb][1][prow][4 + col]  + zsh[0][prow][4 + col]  + zsh[1][prow][4 + col]  + bz[jj][1];
          const float zf = zsx[cb][0][prow][8 + col]  + zsx[cb][1][prow][8 + col]  + zsh[0][prow][8 + col]  + zsh[1][prow][8 + col]  + bz[jj][2];
          const float zo4 = zsx[cb][0][prow][12 + col] + zsx[cb][1][prow][12 + col] + zsh[0][prow][12 + col] + zsh[1][prow][12 + col] + bz[jj][3];
          const float si = 1.f / (1.f + __expf(-zi));
          const float tj = tanhf(zj);
          const float sf = 1.f / (1.f + __expf(-(zf + 1.0f)));  // FORGET_BIAS = 1
          const float so = 1.f / (1.f + __expf(-zo4));
          const float cn = creg[jj] * sf + si * tj;
          hn[jj] = tanhf(cn) * so;
          creg[jj] = cn;
        }
        if (t < NT - 1) {
          // coalesced publish: this wave's 64 u32 = 256 B (4 LLC lines)
          u32 hv = (u32)f2bf(hn[0]) | ((u32)f2bf(hn[1]) << 16);
          u32* hp = reinterpret_cast<u32*>(hseq)
                  + ((size_t)(t + 1) * 256 + b) * 128 + prow * 2 + (pc >> 1);
          __hip_atomic_store(hp, hv, __ATOMIC_RELAXED, __HIP_MEMORY_SCOPE_AGENT);
          asm volatile("s_waitcnt vmcnt(0)" ::: "memory");
        }
        st_rel(&st[8 + hq], (u32)(t + 1));
        if (hq == 0 && t < NT - 1) {
          spin_ge(&st[9], (u32)(t + 1));  // wave 5 drained too
          if (lane == 0)
            __hip_atomic_store(&flags[((size_t)(t + 1) * 256 + b) * FSTR], 1u,
                               __ATOMIC_RELAXED, __HIP_MEMORY_SCOPE_AGENT);
        }
        // staged output (off critical path)
#pragma unroll
        for (int jj = 0; jj < 2; ++jj) {
          __hip_atomic_store(
              reinterpret_cast<u32*>(zo + ((size_t)t * NH + gc0 + jj) * NB + prow),
              __builtin_bit_cast(u32, hn[jj]),
              __ATOMIC_RELAXED, __HIP_MEMORY_SCOPE_AGENT);
        }
      } else {
        // ---- zsh add (waves 6,7); then pre-poll next step ----
        spin_ge(&st[4 + (hq - 2)], (u32)(t + 1));
        if (t > 0) {
#pragma unroll
          for (int i = 0; i < 4; ++i)
#pragma unroll
            for (int r = 0; r < 4; ++r) zsh[hq - 2][i * 16 + mg + r][zn] += acc[i][r];
        }
        st_rel(&st[4 + hq], (u32)(t + 1));   // st[6], st[7]
      }
    }
  }

  // ================= final: grid rendezvous, then zo -> out transpose =========
  __syncthreads();
  asm volatile("s_waitcnt vmcnt(0)" ::: "memory");  // all zo stores at LLC
  if (tid == 0)
    __hip_atomic_store(&flags[(size_t)b * FSTR], 1u, __ATOMIC_RELAXED,
                       __HIP_MEMORY_SCOPE_AGENT);  // done flag (t=0 region)
  if (wv_ == 0) {
    bool ok;
    do {
      u32 v0 = __hip_atomic_load(flags + (size_t)(lane * 4 + 0) * FSTR, __ATOMIC_RELAXED, __HIP_MEMORY_SCOPE_AGENT);
      u32 v1 = __hip_atomic_load(flags + (size_t)(lane * 4 + 1) * FSTR, __ATOMIC_RELAXED, __HIP_MEMORY_SCOPE_AGENT);
      u32 v2 = __hip_atomic_load(flags + (size_t)(lane * 4 + 2) * FSTR, __ATOMIC_RELAXED, __HIP_MEMORY_SCOPE_AGENT);
      u32 v3 = __hip_atomic_load(flags + (size_t)(lane * 4 + 3) * FSTR, __ATOMIC_RELAXED, __HIP_MEMORY_SCOPE_AGENT);
      ok = ((v0 & v1 & v2 & v3) == 1u);
      if (!__all(ok)) __builtin_amdgcn_s_sleep(1);
    } while (!__all(ok));
  }
  __syncthreads();

  // block b: slab ts = b>>1, rows [r0, r0+32). LDS tile reuses the W region.
  {
    const int ts = b >> 1;
    const int r0 = (b & 1) * 32;
    float* T = (float*)smem;  // [32][1028] floats = 131584 B < SMEM_BYTES
#pragma unroll 4
    for (int it = 0; it < 16; ++it) {
      int flat = it * 512 + tid;
      int c = flat >> 3;
      int q = flat & 7;
      const u64* p = reinterpret_cast<const u64*>(
          zo + ((size_t)ts * NH + c) * NB + r0 + q * 4);
      u64 lo = __hip_atomic_load(p + 0, __ATOMIC_RELAXED, __HIP_MEMORY_SCOPE_AGENT);
      u64 hi = __hip_atomic_load(p + 1, __ATOMIC_RELAXED, __HIP_MEMORY_SCOPE_AGENT);
      T[(q * 4 + 0) * 1028 + c] = __builtin_bit_cast(float, (u32)lo);
      T[(q * 4 + 1) * 1028 + c] = __builtin_bit_cast(float, (u32)(lo >> 32));
      T[(q * 4 + 2) * 1028 + c] = __builtin_bit_cast(float, (u32)hi);
      T[(q * 4 + 3) * 1028 + c] = __builtin_bit_cast(float, (u32)(hi >> 32));
    }
    __syncthreads();
#pragma unroll 4
    for (int it = 0; it < 16; ++it) {
      int flat = it * 512 + tid;
      int r = flat >> 8;
      int c4 = flat & 255;
      float4 v;
      v.x = T[r * 1028 + c4 * 4 + 0];
      v.y = T[r * 1028 + c4 * 4 + 1];
      v.z = T[r * 1028 + c4 * 4 + 2];
      v.w = T[r * 1028 + c4 * 4 + 3];
      *reinterpret_cast<float4*>(
          out + ((size_t)(r0 + r) * NT + ts) * NH + c4 * 4) = v;
    }
  }
}

extern "C" void kernel_launch(void* const* d_in, const int* in_sizes, int n_in,
                              void* d_out, int out_size, void* d_ws, size_t ws_size,
                              hipStream_t stream) {
  const float* x = (const float*)d_in[0];
  const float* W = (const float*)d_in[1];
  const float* bias = (const float*)d_in[2];
  float* out = (float*)d_out;

  char* ws = (char*)d_ws;
  u16* xb = (u16*)(ws);                                  // 16 MiB
  u16* wt_blk = (u16*)(ws + 16777216);                   // 32 MiB
  u16* hseq = (u16*)(ws + 50331648);                     // 16 MiB (slab layout)
  u32* flags = (u32*)(ws + 67108864);                    // 2 MiB (line-padded)
  float* zo = (float*)(ws + 69206016);                   // 32 MiB (col-major staging)

  hipMemsetAsync(hseq, 0, 256 * 512, stream);                       // h_0 slabs = 0
  hipMemsetAsync(flags, 0, (size_t)NT * 256 * FSTR * 4, stream);    // per-replay

  lstm_cvt_x<<<(NB * NT * NF) / (256 * 4), 256, 0, stream>>>(x, xb);
  lstm_prep_w<<<dim3(NG / 32, NK / 32), 256, 0, stream>>>(W, wt_blk);

  hipFuncSetAttribute((const void*)lstm_persist,
                      hipFuncAttributeMaxDynamicSharedMemorySize, SMEM_BYTES);

  void* args[] = {(void*)&xb, (void*)&hseq, (void*)&wt_blk, (void*)&bias,
                  (void*)&out, (void*)&flags, (void*)&zo};
  hipLaunchCooperativeKernel((void*)lstm_persist, dim3(256), dim3(512), args,
                             SMEM_BYTES, stream);
}